// Round 11
// baseline (229.172 us; speedup 1.0000x reference)
//
#include <hip/hip_runtime.h>
#include <cstdint>

typedef unsigned short u16;
typedef uint32_t u32;
typedef float f32x4 __attribute__((ext_vector_type(4)));
typedef short s16x8 __attribute__((ext_vector_type(8)));
typedef u16 u16x4 __attribute__((ext_vector_type(4)));
typedef u32 u32x2 __attribute__((ext_vector_type(2)));
typedef u32 u32x4 __attribute__((ext_vector_type(4)));

__device__ __forceinline__ u16 f2bf(float f) {
  u32 u = __builtin_bit_cast(u32, f);
  u += 0x7FFFu + ((u >> 16) & 1u);
  return (u16)(u >> 16);
}

// pack two floats to (bf16(hi)<<16)|bf16(lo), truncating (bias cancels in p/sum ratio)
__device__ __forceinline__ u32 pack2bf_trunc(float lo, float hi) {
  return __builtin_amdgcn_perm(__builtin_bit_cast(u32, hi),
                               __builtin_bit_cast(u32, lo), 0x07060302u);
}

template <typename T>
__device__ __forceinline__ T ldv(const void* p) {
  T v;
  __builtin_memcpy(&v, __builtin_assume_aligned(p, 16), sizeof(T));
  return v;
}

__device__ __forceinline__ void gload_lds16(const void* g, void* l) {
  __builtin_amdgcn_global_load_lds((const __attribute__((address_space(1))) void*)g,
                                   (__attribute__((address_space(3))) void*)l, 16, 0, 0);
}

// ---------------- convert x (fp32 -> bf16) ----------------
__global__ __launch_bounds__(256) void cvt_x_k(const float* __restrict__ in,
                                               u16* __restrict__ out) {
  const int i = (blockIdx.x * 256 + threadIdx.x) * 4;
  float4 v = *(const float4*)(in + i);
  u16x4 o;
  o.x = f2bf(v.x); o.y = f2bf(v.y); o.z = f2bf(v.z); o.w = f2bf(v.w);
  *(u16x4*)(out + i) = o;
}

// ---------------- transpose weights (fp32 [K][N] -> bf16 [N][K]) ----------------
__global__ __launch_bounds__(256) void prep_w_k(const float* __restrict__ Wq,
                                                const float* __restrict__ Wk,
                                                const float* __restrict__ Wv,
                                                const float* __restrict__ Wo,
                                                u16* __restrict__ out) {
  __shared__ u16 t[64][72];
  const float* W = (blockIdx.z == 0) ? Wq : (blockIdx.z == 1) ? Wk
                  : (blockIdx.z == 2) ? Wv : Wo;
  u16* O = out + (size_t)blockIdx.z * 1024 * 1024;
  const int n0 = blockIdx.x * 64, k0 = blockIdx.y * 64;
  const int tid = threadIdx.x;
#pragma unroll
  for (int i = 0; i < 16; ++i) {
    int e = i * 256 + tid;
    int r = e >> 6, c = e & 63;
    t[r][c] = f2bf(W[(size_t)(k0 + r) * 1024 + n0 + c]);
  }
  __syncthreads();
#pragma unroll
  for (int i = 0; i < 16; ++i) {
    int e = i * 256 + tid;
    int rr = e >> 6, cc = e & 63;
    O[(size_t)(n0 + rr) * 1024 + k0 + cc] = t[cc][rr];
  }
}

// ---------------- 256x256 8-phase GEMM (m201-style) ----------------
// OMODE 0: QKV. grid (32, 12): seg = y>>2 in {Q,K,V}, n0 = (y&3)*256.
// OMODE 1: O-proj. grid (32, 4), fp32 out [8192][1024].
// 8 waves (2M x 4N), per-wave C = 128x64, acc[8][4]. BK=64, dbuf LDS 128KB.
// Per K-tile: 4 phases (one C-quadrant, 16 MFMA each). Staging 1 half-tile/phase:
// {A-h0(t+1), A-h1(t+1), B-h0(t+2), B-h1(t+2)}; B-frags reg-resident from phase 0.
// vmcnt ledger (per-thread): steady-state queue at tile-t q3 = [B(t+1):4][A(t+1):4]
// [B(t+2):4]; vmcnt(4) retires B(t+1)+A(t+1), leaves B(t+2) in flight.
// PROLOGUE stages B(t0), A(t0), AND B(t1) (Bs[1] — this was the round-9 NaN hole),
// vmcnt(4) leaves B(t1) in flight. T2 swizzle both-sides; T5 setprio.
template <int OMODE>
__global__ __launch_bounds__(512, 2) void gemm8p_k(const u16* __restrict__ A,
                                                   const u16* __restrict__ Wt,
                                                   const float* __restrict__ bq,
                                                   const float* __restrict__ bk,
                                                   const float* __restrict__ bv,
                                                   u16* __restrict__ Qh,
                                                   u16* __restrict__ Kh,
                                                   u16* __restrict__ Vt,
                                                   float* __restrict__ Oo,
                                                   float qscale) {
  __shared__ __attribute__((aligned(16))) u16 As[2][2][128][64];
  __shared__ __attribute__((aligned(16))) u16 Bs[2][2][128][64];
  const int tid = threadIdx.x;
  const int l = tid & 63, w = tid >> 6;
  const int lr = l & 15, lg = l >> 4;
  const int wm = w >> 2, wn = w & 3;           // 2M x 4N wave grid
  const int m0 = blockIdx.x * 256;
  int seg, n0;
  if constexpr (OMODE == 0) { seg = blockIdx.y >> 2; n0 = (blockIdx.y & 3) * 256; }
  else { seg = 3; n0 = blockIdx.y * 256; }
  const u16* Bt = Wt + ((size_t)seg << 20);
  const int rT = tid >> 3;                      // 0..63 staging row
  const int cSw = (((tid & 7) ^ (rT & 7)) << 3);  // pre-swizzled src col
  const int xk = lr & 7;                        // read-side XOR key

  f32x4 acc[8][4] = {};
  s16x8 bfr[4][2];

#define STG_A(buf, h, kt)                                                       \
  do {                                                                          \
    gload_lds16(A + (size_t)(m0 + (h) * 128 + rT) * 1024 + (kt) + cSw,          \
                &As[buf][h][0][0] + w * 512);                                   \
    gload_lds16(A + (size_t)(m0 + (h) * 128 + 64 + rT) * 1024 + (kt) + cSw,     \
                &As[buf][h][64][0] + w * 512);                                  \
  } while (0)
#define STG_B(buf, h, kt)                                                       \
  do {                                                                          \
    gload_lds16(Bt + (size_t)(n0 + (h) * 128 + rT) * 1024 + (kt) + cSw,         \
                &Bs[buf][h][0][0] + w * 512);                                   \
    gload_lds16(Bt + (size_t)(n0 + (h) * 128 + 64 + rT) * 1024 + (kt) + cSw,    \
                &Bs[buf][h][64][0] + w * 512);                                  \
  } while (0)

  // prologue: B(t0), A(t0) drained; B(t1) left in flight (4 loads)
  STG_B(0, 0, 0); STG_B(0, 1, 0);
  STG_A(0, 0, 0); STG_A(0, 1, 0);
  STG_B(1, 0, 64); STG_B(1, 1, 64);
  asm volatile("s_waitcnt vmcnt(4)" ::: "memory");
  __builtin_amdgcn_sched_barrier(0);
  __builtin_amdgcn_s_barrier();
  __builtin_amdgcn_sched_barrier(0);

#pragma unroll 2
  for (int t = 0; t < 16; ++t) {
    const int cur = t & 1;
    const int kt1 = (t + 1) * 64, kt2 = (t + 2) * 64;
#pragma unroll
    for (int q = 0; q < 4; ++q) {
      // ---- ds reads for this phase ----
      s16x8 aq[2][2];
#pragma unroll
      for (int sub = 0; sub < 2; ++sub)
#pragma unroll
        for (int kk = 0; kk < 2; ++kk)
          aq[sub][kk] = ldv<s16x8>(
              &As[cur][wm][q * 32 + sub * 16 + lr][((kk * 4 + lg) ^ xk) << 3]);
      if (q == 0) {
#pragma unroll
        for (int ni = 0; ni < 4; ++ni)
#pragma unroll
          for (int kk = 0; kk < 2; ++kk)
            bfr[ni][kk] = ldv<s16x8>(
                &Bs[cur][wn >> 1][(wn & 1) * 64 + ni * 16 + lr][((kk * 4 + lg) ^ xk) << 3]);
      }
      // ---- stage one half-tile ----
      if (q == 0)      { if (t < 15) STG_A(cur ^ 1, 0, kt1); }
      else if (q == 1) { if (t < 15) STG_A(cur ^ 1, 1, kt1); }
      else if (q == 2) { if (t < 14) STG_B(cur, 0, kt2); }
      else             { if (t < 14) STG_B(cur, 1, kt2); }
      __builtin_amdgcn_sched_barrier(0);
      __builtin_amdgcn_s_barrier();   // barrier 1: reads+stage issued
      __builtin_amdgcn_sched_barrier(0);
      __builtin_amdgcn_s_setprio(1);
#pragma unroll
      for (int kk = 0; kk < 2; ++kk)
#pragma unroll
        for (int sub = 0; sub < 2; ++sub)
#pragma unroll
          for (int ni = 0; ni < 4; ++ni)
            acc[q * 2 + sub][ni] = __builtin_amdgcn_mfma_f32_16x16x32_bf16(
                aq[sub][kk], bfr[ni][kk], acc[q * 2 + sub][ni], 0, 0, 0);
      __builtin_amdgcn_s_setprio(0);
      if (q == 3) {
        if (t < 14) asm volatile("s_waitcnt vmcnt(4)" ::: "memory");  // B(t+1),A(t+1) landed
        else        asm volatile("s_waitcnt vmcnt(0)" ::: "memory");
      }
      __builtin_amdgcn_sched_barrier(0);
      __builtin_amdgcn_s_barrier();   // barrier 2: phase reads retired before overwrites
      __builtin_amdgcn_sched_barrier(0);
    }
  }
#undef STG_A
#undef STG_B

  if constexpr (OMODE == 1) {
#pragma unroll
    for (int ni = 0; ni < 4; ++ni) {
      const int col = n0 + wn * 64 + ni * 16 + lr;
      const float bvv = bq[col];
#pragma unroll
      for (int mi = 0; mi < 8; ++mi)
#pragma unroll
        for (int r = 0; r < 4; ++r) {
          const int row = m0 + wm * 128 + mi * 16 + lg * 4 + r;
          Oo[(size_t)row * 1024 + col] = acc[mi][ni][r] + bvv;
        }
    }
    return;
  } else {
    const float* bias = (seg == 0) ? bq : (seg == 1) ? bk : bv;
    const float scale = (seg == 0) ? qscale : 1.0f;
    u16* outp = (seg == 0) ? Qh : (seg == 1) ? Kh : Vt;
    u16* Cb = &As[0][0][0][0];  // [256][64] staging
    const int bb = m0 >> 11;
    const int sbase = m0 & 2047;
#pragma unroll
    for (int p = 0; p < 4; ++p) {
      __syncthreads();
      if (wn == p) {  // waves (wm 0,1) with wn==p cover all 256 rows of this 64-col quarter
#pragma unroll
        for (int ni = 0; ni < 4; ++ni) {
          const int c = ni * 16 + lr;
          const float bvv = bias[n0 + p * 64 + c];
#pragma unroll
          for (int mi = 0; mi < 8; ++mi)
#pragma unroll
            for (int r = 0; r < 4; ++r) {
              const int row = wm * 128 + mi * 16 + lg * 4 + r;
              Cb[row * 64 + ((((c >> 3) ^ (row & 7)) << 3) | (c & 7))] =
                  f2bf((acc[mi][ni][r] + bvv) * scale);
            }
        }
      }
      __syncthreads();
      const int h = (n0 + p * 64) >> 6;
      if (seg <= 1) {
        const int row = tid >> 1;
        const int s = sbase + row;
#pragma unroll
        for (int j = 0; j < 4; ++j) {
          const int c = (tid & 1) * 32 + j * 8;
          s16x8 v = ldv<s16x8>(&Cb[row * 64 + (((c >> 3) ^ (row & 7)) << 3)]);
          const int chunk = (seg == 0) ? (c >> 3) : (((c >> 3) ^ (s & 7)) & 7);
          *(s16x8*)(outp + ((size_t)((bb << 4) + h) * 2048 + s) * 64 + (chunk << 3)) = v;
        }
      } else {
        const int hd = tid & 63;
#pragma unroll
        for (int j = 0; j < 4; ++j) {
          const int s0 = (tid >> 6) * 32 + j * 8;
          u16 vals[8];
#pragma unroll
          for (int i = 0; i < 8; ++i) {
            const int row = s0 + i;
            vals[i] = Cb[row * 64 + ((((hd >> 3) ^ (row & 7)) << 3) | (hd & 7))];
          }
          const int sl = sbase + s0;
          const int swz = (((sl >> 3) & 7) ^ (hd & 7)) & 7;
          *(s16x8*)(outp + ((size_t)((bb << 4) + h) * 64 + hd) * 2048 +
                    ((sl & ~63) | (swz << 3))) = *(s16x8*)vals;
        }
      }
    }
  }
}

// ---------------- flash attention v6: no-max softmax + counted-vmcnt dbuf ----------------
// 4 waves/block, wave owns 32 q-rows, grid (16,64). LDS 40960 B.
// Qh: [BH][2048][64] bf16 pre-scaled; Kg same layout, d-chunk swizzled;
// Vg: [BH][64][2048] bf16, s-chunk swizzled. Out: [B*S][1024] bf16.
__global__ __launch_bounds__(256, 4) void attn_k(const u16* __restrict__ Qh,
                                                 const u16* __restrict__ Kg,
                                                 const u16* __restrict__ Vg,
                                                 u16* __restrict__ Oattn) {
  __shared__ __attribute__((aligned(16))) u16 Kbuf[2][4096];
  __shared__ __attribute__((aligned(16))) u16 Vbuf[2][4096];
  __shared__ __attribute__((aligned(16))) u16 P_lds[4][16][64];
  const int tid = threadIdx.x, l = tid & 63, w = tid >> 6;
  const int lr = l & 15, lg = l >> 4;
  const int bh = blockIdx.y;
  const int q0 = blockIdx.x * 128 + w * 32;
  const u16* Q = Qh + (size_t)bh * (2048 * 64);
  const u16* K = Kg + (size_t)bh * (2048 * 64);
  const u16* V = Vg + (size_t)bh * (64 * 2048);

  s16x8 qf[2][2];
#pragma unroll
  for (int f = 0; f < 2; ++f)
#pragma unroll
    for (int kk = 0; kk < 2; ++kk)
      qf[f][kk] = ldv<s16x8>(Q + (size_t)(q0 + f * 16 + lr) * 64 + kk * 32 + lg * 8);

  const u32 one2 = 0x3F803F80u;  // two bf16 1.0
  const s16x8 onesv = __builtin_bit_cast(s16x8, (u32x4){one2, one2, one2, one2});

  f32x4 acc[2][4] = {};
  f32x4 lsum[2] = {};

#define STAGE(buf, kv0)                                                                 \
  do {                                                                                  \
    gload_lds16(K + (size_t)(kv0) * 64 + (size_t)tid * 8, &Kbuf[buf][w * 512]);         \
    gload_lds16(K + (size_t)(kv0) * 64 + 2048 + (size_t)tid * 8,                        \
                &Kbuf[buf][2048 + w * 512]);                                            \
    gload_lds16(V + (size_t)(tid >> 3) * 2048 + (kv0) + (tid & 7) * 8,                  \
                &Vbuf[buf][w * 512]);                                                   \
    gload_lds16(V + (size_t)((tid >> 3) + 32) * 2048 + (kv0) + (tid & 7) * 8,           \
                &Vbuf[buf][2048 + w * 512]);                                            \
  } while (0)

  STAGE(0, 0);

  for (int t = 0; t < 32; ++t) {
    const int cur = t & 1;
    if (t < 31) {
      STAGE(cur ^ 1, (t + 1) * 64);
      asm volatile("s_waitcnt vmcnt(4)" ::: "memory");  // cur's 4 retired
    } else {
      asm volatile("s_waitcnt vmcnt(0)" ::: "memory");
    }
    __builtin_amdgcn_sched_barrier(0);
    __builtin_amdgcn_s_barrier();
    __builtin_amdgcn_sched_barrier(0);

    // ---- QK^T (swapped): lane holds s for q=lr, kv = tt*16 + lg*4 + r ----
    f32x4 s[2][4] = {};
    __builtin_amdgcn_s_setprio(1);
#pragma unroll
    for (int tt = 0; tt < 4; ++tt) {
      s16x8 k0 = ldv<s16x8>(&Kbuf[cur][(tt * 16 + lr) * 64 + ((lg ^ (lr & 7)) << 3)]);
      s16x8 k1 = ldv<s16x8>(&Kbuf[cur][(tt * 16 + lr) * 64 + (((4 + lg) ^ (lr & 7)) << 3)]);
#pragma unroll
      for (int f = 0; f < 2; ++f) {
        s[f][tt] = __builtin_amdgcn_mfma_f32_16x16x32_bf16(k0, qf[f][0], s[f][tt], 0, 0, 0);
        s[f][tt] = __builtin_amdgcn_mfma_f32_16x16x32_bf16(k1, qf[f][1], s[f][tt], 0, 0, 0);
      }
    }
    __builtin_amdgcn_s_setprio(0);

    // ---- p = exp2(s); pack; P_lds roundtrip; lsum via ones-MFMA ----
    s16x8 pf[2][2];
#pragma unroll
    for (int f = 0; f < 2; ++f) {
#pragma unroll
      for (int tt = 0; tt < 4; ++tt)
#pragma unroll
        for (int r = 0; r < 4; ++r)
          s[f][tt][r] = __builtin_amdgcn_exp2f(s[f][tt][r]);
#pragma unroll
      for (int tt = 0; tt < 4; ++tt) {
        u32x2 pw;
        pw.x = pack2bf_trunc(s[f][tt][0], s[f][tt][1]);
        pw.y = pack2bf_trunc(s[f][tt][2], s[f][tt][3]);
        const int off = (((tt * 2 + (lg >> 1)) ^ (lr & 7)) << 3) + ((lg & 1) << 2);
        *(u32x2*)&P_lds[w][lr][off] = pw;
      }
#pragma unroll
      for (int kvc = 0; kvc < 2; ++kvc)
        pf[f][kvc] = ldv<s16x8>(&P_lds[w][lr][((kvc * 4 + lg) ^ (lr & 7)) << 3]);
      lsum[f] = __builtin_amdgcn_mfma_f32_16x16x32_bf16(pf[f][0], onesv, lsum[f], 0, 0, 0);
      lsum[f] = __builtin_amdgcn_mfma_f32_16x16x32_bf16(pf[f][1], onesv, lsum[f], 0, 0, 0);
    }

    // ---- PV ----
    __builtin_amdgcn_s_setprio(1);
#pragma unroll
    for (int dt = 0; dt < 4; ++dt) {
      s16x8 v0 = ldv<s16x8>(&Vbuf[cur][(dt * 16 + lr) * 64 + ((lg ^ (lr & 7)) << 3)]);
      s16x8 v1 = ldv<s16x8>(&Vbuf[cur][(dt * 16 + lr) * 64 + (((4 + lg) ^ (lr & 7)) << 3)]);
#pragma unroll
      for (int f = 0; f < 2; ++f) {
        acc[f][dt] = __builtin_amdgcn_mfma_f32_16x16x32_bf16(pf[f][0], v0, acc[f][dt], 0, 0, 0);
        acc[f][dt] = __builtin_amdgcn_mfma_f32_16x16x32_bf16(pf[f][1], v1, acc[f][dt], 0, 0, 0);
      }
    }
    __builtin_amdgcn_s_setprio(0);
    __builtin_amdgcn_sched_barrier(0);
    __builtin_amdgcn_s_barrier();
  }
#undef STAGE

  const int b = bh >> 4, h = bh & 15;
#pragma unroll
  for (int f = 0; f < 2; ++f) {
    float li[4];
#pragma unroll
    for (int r = 0; r < 4; ++r) li[r] = __builtin_amdgcn_rcpf(lsum[f][r]);
#pragma unroll
    for (int dt = 0; dt < 4; ++dt)
#pragma unroll
      for (int r = 0; r < 4; ++r) {
        const int q = q0 + f * 16 + lg * 4 + r;
        Oattn[(size_t)((b << 11) + q) * 1024 + (h << 6) + dt * 16 + lr] =
            f2bf(acc[f][dt][r] * li[r]);
      }
  }
}

extern "C" void kernel_launch(void* const* d_in, const int* in_sizes, int n_in,
                              void* d_out, int out_size, void* d_ws, size_t ws_size,
                              hipStream_t stream) {
  const float* x  = (const float*)d_in[0];
  const float* Wq = (const float*)d_in[1];
  const float* bq = (const float*)d_in[2];
  const float* Wk = (const float*)d_in[3];
  const float* bk = (const float*)d_in[4];
  const float* Wv = (const float*)d_in[5];
  const float* bv = (const float*)d_in[6];
  const float* Wo = (const float*)d_in[7];
  const float* bo = (const float*)d_in[8];

  char* ws = (char*)d_ws;
  const size_t MB = 1u << 20;
  u16* xb = (u16*)(ws);              // 16 MB: x bf16 [8192][1024]
  u16* wt = (u16*)(ws + 16 * MB);    // 8 MB: 4x transposed bf16 weights [N][K]
  u16* Qh = (u16*)(ws + 24 * MB);    // 16 MB
  u16* Kh = (u16*)(ws + 40 * MB);    // 16 MB (swizzled)
  u16* Vt = (u16*)(ws + 56 * MB);    // 16 MB (transposed, swizzled)
  u16* attn = xb;                    // alias: x no longer needed after QKV GEMM

  const float qscale = 0.125f * 1.44269504088896f;  // fold 1/sqrt(64) and log2(e)

  cvt_x_k<<<dim3(8192), dim3(256), 0, stream>>>(x, xb);
  prep_w_k<<<dim3(16, 16, 4), dim3(256), 0, stream>>>(Wq, Wk, Wv, Wo, wt);
  gemm8p_k<0><<<dim3(32, 12), dim3(512), 0, stream>>>(xb, wt, bq, bk, bv, Qh, Kh, Vt,
                                                      nullptr, qscale);
  attn_k<<<dim3(16, 64), dim3(256), 0, stream>>>(Qh, Kh, Vt, attn);
  gemm8p_k<1><<<dim3(32, 4), dim3(512), 0, stream>>>(attn, wt, bo, nullptr, nullptr,
                                                     nullptr, nullptr, nullptr,
                                                     (float*)d_out, 1.0f);
}

// Round 12
// 210.896 us; speedup vs baseline: 1.0867x; 1.0867x over previous
//
#include <hip/hip_runtime.h>
#include <cstdint>

typedef unsigned short u16;
typedef uint32_t u32;
typedef float f32x4 __attribute__((ext_vector_type(4)));
typedef short s16x8 __attribute__((ext_vector_type(8)));
typedef u16 u16x4 __attribute__((ext_vector_type(4)));
typedef u32 u32x2 __attribute__((ext_vector_type(2)));
typedef u32 u32x4 __attribute__((ext_vector_type(4)));

__device__ __forceinline__ u16 f2bf(float f) {
  u32 u = __builtin_bit_cast(u32, f);
  u += 0x7FFFu + ((u >> 16) & 1u);
  return (u16)(u >> 16);
}

// pack two floats to (bf16(hi)<<16)|bf16(lo), truncating (bias cancels in p/sum ratio)
__device__ __forceinline__ u32 pack2bf_trunc(float lo, float hi) {
  return __builtin_amdgcn_perm(__builtin_bit_cast(u32, hi),
                               __builtin_bit_cast(u32, lo), 0x07060302u);
}

template <typename T>
__device__ __forceinline__ T ldv(const void* p) {
  T v;
  __builtin_memcpy(&v, __builtin_assume_aligned(p, 16), sizeof(T));
  return v;
}

__device__ __forceinline__ void gload_lds16(const void* g, void* l) {
  __builtin_amdgcn_global_load_lds((const __attribute__((address_space(1))) void*)g,
                                   (__attribute__((address_space(3))) void*)l, 16, 0, 0);
}

// ---------------- convert x (fp32 -> bf16) ----------------
__global__ __launch_bounds__(256) void cvt_x_k(const float* __restrict__ in,
                                               u16* __restrict__ out) {
  const int i = (blockIdx.x * 256 + threadIdx.x) * 4;
  float4 v = *(const float4*)(in + i);
  u16x4 o;
  o.x = f2bf(v.x); o.y = f2bf(v.y); o.z = f2bf(v.z); o.w = f2bf(v.w);
  *(u16x4*)(out + i) = o;
}

// ---------------- transpose weights (fp32 [K][N] -> bf16 [N][K]) ----------------
__global__ __launch_bounds__(256) void prep_w_k(const float* __restrict__ Wq,
                                                const float* __restrict__ Wk,
                                                const float* __restrict__ Wv,
                                                const float* __restrict__ Wo,
                                                u16* __restrict__ out) {
  __shared__ u16 t[64][72];
  const float* W = (blockIdx.z == 0) ? Wq : (blockIdx.z == 1) ? Wk
                  : (blockIdx.z == 2) ? Wv : Wo;
  u16* O = out + (size_t)blockIdx.z * 1024 * 1024;
  const int n0 = blockIdx.x * 64, k0 = blockIdx.y * 64;
  const int tid = threadIdx.x;
#pragma unroll
  for (int i = 0; i < 16; ++i) {
    int e = i * 256 + tid;
    int r = e >> 6, c = e & 63;
    t[r][c] = f2bf(W[(size_t)(k0 + r) * 1024 + n0 + c]);
  }
  __syncthreads();
#pragma unroll
  for (int i = 0; i < 16; ++i) {
    int e = i * 256 + tid;
    int rr = e >> 6, cc = e & 63;
    O[(size_t)(n0 + rr) * 1024 + k0 + cc] = t[cc][rr];
  }
}

// ---------------- fused QKV GEMM: 256x128 tile, 8 waves, TRIPLE-buffered LDS ----------------
// Depth-2 prefetch: stage S(t+2) each iter; vmcnt(12) keeps 2 tiles (12 loads/thread)
// in flight -> ~2x outstanding bytes per CU vs dbuf (ingest-rate theory, r11).
// grid (32, 24): y -> 128-col block of [Wq;Wk;Wv]. seg = y>>3.
// seg 0 (Q): bf16 [BH][S][64] scaled; seg 1: same, d-chunk swz; seg 2: [BH][64][S], s-chunk swz.
// T2 swizzle both-sides: pre-swizzled global src col, linear gload_lds dest, XOR on ds_read.
__global__ __launch_bounds__(512, 2) void gemm_qkv_k(const u16* __restrict__ A,
                                                     const u16* __restrict__ Wt,
                                                     const float* __restrict__ bq,
                                                     const float* __restrict__ bk,
                                                     const float* __restrict__ bv,
                                                     u16* __restrict__ Qh,
                                                     u16* __restrict__ Kh,
                                                     u16* __restrict__ Vt,
                                                     float qscale) {
  constexpr int K = 1024;
  __shared__ __attribute__((aligned(16))) u16 As[3][256][64];
  __shared__ __attribute__((aligned(16))) u16 Bs[3][128][64];
  const int tid = threadIdx.x;
  const int l = tid & 63, w = tid >> 6;
  const int lr = l & 15, lg = l >> 4;
  const int m0 = blockIdx.x * 256;
  const int ng = blockIdx.y * 128;
  const int seg = ng >> 10;
  const int n0 = ng & 1023;
  const u16* Bt = Wt + ((size_t)seg << 20);
  const int wr = (w >> 1) * 64, wc = (w & 1) * 64;  // 4M x 2N wave grid
  const int rT = tid >> 3;                            // 0..63 staging row
  const int cSw = (((tid & 7) ^ (rT & 7)) << 3);      // pre-swizzled src col

  f32x4 acc[4][4] = {};

#define GSTAGE(buf, kt)                                                         \
  do {                                                                          \
    _Pragma("unroll")                                                           \
    for (int i = 0; i < 4; ++i)                                                 \
      gload_lds16(A + (size_t)(m0 + i * 64 + rT) * K + (kt) + cSw,              \
                  &As[buf][i * 64][0] + (size_t)w * 512);                       \
    _Pragma("unroll")                                                           \
    for (int i = 0; i < 2; ++i)                                                 \
      gload_lds16(Bt + (size_t)(n0 + i * 64 + rT) * K + (kt) + cSw,             \
                  &Bs[buf][i * 64][0] + (size_t)w * 512);                       \
  } while (0)

  // prologue: S0, S1 issued (12 outstanding); retire S0, keep S1 in flight
  GSTAGE(0, 0);
  GSTAGE(1, 64);
  asm volatile("s_waitcnt vmcnt(6)" ::: "memory");
  __builtin_amdgcn_sched_barrier(0);
  __builtin_amdgcn_s_barrier();
  __builtin_amdgcn_sched_barrier(0);

  int bcur = 0, bst = 2;  // bst = (t+2)%3
  for (int t = 0; t < 16; ++t) {
    if (t < 14) {
      GSTAGE(bst, (t + 2) * 64);
      asm volatile("s_waitcnt vmcnt(12)" ::: "memory");  // S(t) retired; S(t+1),S(t+2) in flight
    } else if (t == 14) {
      asm volatile("s_waitcnt vmcnt(6)" ::: "memory");   // S(14) retired
    } else {
      asm volatile("s_waitcnt vmcnt(0)" ::: "memory");
    }
    __builtin_amdgcn_sched_barrier(0);
    __builtin_amdgcn_s_barrier();
    __builtin_amdgcn_sched_barrier(0);
#pragma unroll
    for (int kk = 0; kk < 2; ++kk) {
      s16x8 a[4], b[4];
#pragma unroll
      for (int mi = 0; mi < 4; ++mi)
        a[mi] = ldv<s16x8>(&As[bcur][wr + mi * 16 + lr][((kk * 4 + lg) ^ (lr & 7)) << 3]);
#pragma unroll
      for (int ni = 0; ni < 4; ++ni)
        b[ni] = ldv<s16x8>(&Bs[bcur][wc + ni * 16 + lr][((kk * 4 + lg) ^ (lr & 7)) << 3]);
#pragma unroll
      for (int mi = 0; mi < 4; ++mi)
#pragma unroll
        for (int ni = 0; ni < 4; ++ni)
          acc[mi][ni] = __builtin_amdgcn_mfma_f32_16x16x32_bf16(a[mi], b[ni], acc[mi][ni], 0, 0, 0);
    }
    __builtin_amdgcn_sched_barrier(0);
    __builtin_amdgcn_s_barrier();  // reads of buf t retired before its overwrite (issued t+1)
    bcur = (bcur == 2) ? 0 : bcur + 1;
    bst = (bst == 2) ? 0 : bst + 1;
  }
#undef GSTAGE

  const float* bias = (seg == 0) ? bq : (seg == 1) ? bk : bv;
  const float scale = (seg == 0) ? qscale : 1.0f;
  u16* outp = (seg == 0) ? Qh : (seg == 1) ? Kh : Vt;

  // ---- coalesced epilogue via swizzled LDS staging (reuse As[0]: [256][64]) ----
  u16* Cb = &As[0][0][0];
  const int bb = m0 >> 11;
  const int sbase = m0 & 2047;

#pragma unroll
  for (int p = 0; p < 2; ++p) {
    __syncthreads();
    if ((wc >> 6) == p) {
#pragma unroll
      for (int ni = 0; ni < 4; ++ni) {
        const int c = ni * 16 + lr;
        const float bvv = bias[n0 + p * 64 + c];
#pragma unroll
        for (int mi = 0; mi < 4; ++mi) {
#pragma unroll
          for (int r = 0; r < 4; ++r) {
            const int row = wr + mi * 16 + lg * 4 + r;
            Cb[row * 64 + ((((c >> 3) ^ (row & 7)) << 3) | (c & 7))] =
                f2bf((acc[mi][ni][r] + bvv) * scale);
          }
        }
      }
    }
    __syncthreads();
    const int h = (n0 + p * 64) >> 6;
    if (seg <= 1) {
      const int row = tid >> 1;  // 0..255
      const int s = sbase + row;
#pragma unroll
      for (int j = 0; j < 4; ++j) {
        const int c = (tid & 1) * 32 + j * 8;
        s16x8 v = ldv<s16x8>(&Cb[row * 64 + (((c >> 3) ^ (row & 7)) << 3)]);
        const int chunk = (seg == 0) ? (c >> 3) : (((c >> 3) ^ (s & 7)) & 7);
        *(s16x8*)(outp + ((size_t)((bb << 4) + h) * 2048 + s) * 64 + (chunk << 3)) = v;
      }
    } else {
      const int hd = tid & 63;
#pragma unroll
      for (int j = 0; j < 4; ++j) {
        const int s0 = (tid >> 6) * 32 + j * 8;  // 0..248
        u16 vals[8];
#pragma unroll
        for (int i = 0; i < 8; ++i) {
          const int row = s0 + i;
          vals[i] = Cb[row * 64 + ((((hd >> 3) ^ (row & 7)) << 3) | (hd & 7))];
        }
        const int sl = sbase + s0;
        const int swz = (((sl >> 3) & 7) ^ (hd & 7)) & 7;
        *(s16x8*)(outp + ((size_t)((bb << 4) + h) * 64 + hd) * 2048 +
                  ((sl & ~63) | (swz << 3))) = *(s16x8*)vals;
      }
    }
  }
}

// ---------------- final GEMM: 256x128 tile, 8 waves, triple-buffered, fp32 out ----------------
// grid (32, 8) = 256 blocks = exactly 1 round
__global__ __launch_bounds__(512, 2) void gemm_o_k(const u16* __restrict__ A,
                                                   const u16* __restrict__ Bt,
                                                   const float* __restrict__ bias,
                                                   float* __restrict__ outp) {
  constexpr int K = 1024;
  __shared__ __attribute__((aligned(16))) u16 As[3][256][64];
  __shared__ __attribute__((aligned(16))) u16 Bs[3][128][64];
  const int tid = threadIdx.x;
  const int l = tid & 63, w = tid >> 6;
  const int lr = l & 15, lg = l >> 4;
  const int m0 = blockIdx.x * 256, n0 = blockIdx.y * 128;
  const int wr = (w >> 1) * 64, wc = (w & 1) * 64;
  const int rT = tid >> 3;
  const int cSw = (((tid & 7) ^ (rT & 7)) << 3);

  f32x4 acc[4][4] = {};

#define GSTAGE(buf, kt)                                                         \
  do {                                                                          \
    _Pragma("unroll")                                                           \
    for (int i = 0; i < 4; ++i)                                                 \
      gload_lds16(A + (size_t)(m0 + i * 64 + rT) * K + (kt) + cSw,              \
                  &As[buf][i * 64][0] + (size_t)w * 512);                       \
    _Pragma("unroll")                                                           \
    for (int i = 0; i < 2; ++i)                                                 \
      gload_lds16(Bt + (size_t)(n0 + i * 64 + rT) * K + (kt) + cSw,             \
                  &Bs[buf][i * 64][0] + (size_t)w * 512);                       \
  } while (0)

  GSTAGE(0, 0);
  GSTAGE(1, 64);
  asm volatile("s_waitcnt vmcnt(6)" ::: "memory");
  __builtin_amdgcn_sched_barrier(0);
  __builtin_amdgcn_s_barrier();
  __builtin_amdgcn_sched_barrier(0);

  int bcur = 0, bst = 2;
  for (int t = 0; t < 16; ++t) {
    if (t < 14) {
      GSTAGE(bst, (t + 2) * 64);
      asm volatile("s_waitcnt vmcnt(12)" ::: "memory");
    } else if (t == 14) {
      asm volatile("s_waitcnt vmcnt(6)" ::: "memory");
    } else {
      asm volatile("s_waitcnt vmcnt(0)" ::: "memory");
    }
    __builtin_amdgcn_sched_barrier(0);
    __builtin_amdgcn_s_barrier();
    __builtin_amdgcn_sched_barrier(0);
#pragma unroll
    for (int kk = 0; kk < 2; ++kk) {
      s16x8 a[4], b[4];
#pragma unroll
      for (int mi = 0; mi < 4; ++mi)
        a[mi] = ldv<s16x8>(&As[bcur][wr + mi * 16 + lr][((kk * 4 + lg) ^ (lr & 7)) << 3]);
#pragma unroll
      for (int ni = 0; ni < 4; ++ni)
        b[ni] = ldv<s16x8>(&Bs[bcur][wc + ni * 16 + lr][((kk * 4 + lg) ^ (lr & 7)) << 3]);
#pragma unroll
      for (int mi = 0; mi < 4; ++mi)
#pragma unroll
        for (int ni = 0; ni < 4; ++ni)
          acc[mi][ni] = __builtin_amdgcn_mfma_f32_16x16x32_bf16(a[mi], b[ni], acc[mi][ni], 0, 0, 0);
    }
    __builtin_amdgcn_sched_barrier(0);
    __builtin_amdgcn_s_barrier();
    bcur = (bcur == 2) ? 0 : bcur + 1;
    bst = (bst == 2) ? 0 : bst + 1;
  }
#undef GSTAGE

#pragma unroll
  for (int ni = 0; ni < 4; ++ni) {
    const int col = n0 + wc + ni * 16 + lr;
    const float bv = bias[col];
#pragma unroll
    for (int mi = 0; mi < 4; ++mi)
#pragma unroll
      for (int r = 0; r < 4; ++r) {
        const int rowm = m0 + wr + mi * 16 + lg * 4 + r;
        outp[(size_t)rowm * 1024 + col] = acc[mi][ni][r] + bv;
      }
  }
}

// ---------------- flash attention v6: no-max softmax + counted-vmcnt dbuf ----------------
// 4 waves/block, wave owns 32 q-rows, grid (16,64). LDS 40960 B.
// Qh: [BH][2048][64] bf16 pre-scaled; Kg same layout, d-chunk swizzled;
// Vg: [BH][64][2048] bf16, s-chunk swizzled. Out: [B*S][1024] bf16.
__global__ __launch_bounds__(256, 4) void attn_k(const u16* __restrict__ Qh,
                                                 const u16* __restrict__ Kg,
                                                 const u16* __restrict__ Vg,
                                                 u16* __restrict__ Oattn) {
  __shared__ __attribute__((aligned(16))) u16 Kbuf[2][4096];
  __shared__ __attribute__((aligned(16))) u16 Vbuf[2][4096];
  __shared__ __attribute__((aligned(16))) u16 P_lds[4][16][64];
  const int tid = threadIdx.x, l = tid & 63, w = tid >> 6;
  const int lr = l & 15, lg = l >> 4;
  const int bh = blockIdx.y;
  const int q0 = blockIdx.x * 128 + w * 32;
  const u16* Q = Qh + (size_t)bh * (2048 * 64);
  const u16* K = Kg + (size_t)bh * (2048 * 64);
  const u16* V = Vg + (size_t)bh * (64 * 2048);

  s16x8 qf[2][2];
#pragma unroll
  for (int f = 0; f < 2; ++f)
#pragma unroll
    for (int kk = 0; kk < 2; ++kk)
      qf[f][kk] = ldv<s16x8>(Q + (size_t)(q0 + f * 16 + lr) * 64 + kk * 32 + lg * 8);

  const u32 one2 = 0x3F803F80u;  // two bf16 1.0
  const s16x8 onesv = __builtin_bit_cast(s16x8, (u32x4){one2, one2, one2, one2});

  f32x4 acc[2][4] = {};
  f32x4 lsum[2] = {};

#define STAGE(buf, kv0)                                                                 \
  do {                                                                                  \
    gload_lds16(K + (size_t)(kv0) * 64 + (size_t)tid * 8, &Kbuf[buf][w * 512]);         \
    gload_lds16(K + (size_t)(kv0) * 64 + 2048 + (size_t)tid * 8,                        \
                &Kbuf[buf][2048 + w * 512]);                                            \
    gload_lds16(V + (size_t)(tid >> 3) * 2048 + (kv0) + (tid & 7) * 8,                  \
                &Vbuf[buf][w * 512]);                                                   \
    gload_lds16(V + (size_t)((tid >> 3) + 32) * 2048 + (kv0) + (tid & 7) * 8,           \
                &Vbuf[buf][2048 + w * 512]);                                            \
  } while (0)

  STAGE(0, 0);

  for (int t = 0; t < 32; ++t) {
    const int cur = t & 1;
    if (t < 31) {
      STAGE(cur ^ 1, (t + 1) * 64);
      asm volatile("s_waitcnt vmcnt(4)" ::: "memory");  // cur's 4 retired
    } else {
      asm volatile("s_waitcnt vmcnt(0)" ::: "memory");
    }
    __builtin_amdgcn_sched_barrier(0);
    __builtin_amdgcn_s_barrier();
    __builtin_amdgcn_sched_barrier(0);

    // ---- QK^T (swapped): lane holds s for q=lr, kv = tt*16 + lg*4 + r ----
    f32x4 s[2][4] = {};
    __builtin_amdgcn_s_setprio(1);
#pragma unroll
    for (int tt = 0; tt < 4; ++tt) {
      s16x8 k0 = ldv<s16x8>(&Kbuf[cur][(tt * 16 + lr) * 64 + ((lg ^ (lr & 7)) << 3)]);
      s16x8 k1 = ldv<s16x8>(&Kbuf[cur][(tt * 16 + lr) * 64 + (((4 + lg) ^ (lr & 7)) << 3)]);
#pragma unroll
      for (int f = 0; f < 2; ++f) {
        s[f][tt] = __builtin_amdgcn_mfma_f32_16x16x32_bf16(k0, qf[f][0], s[f][tt], 0, 0, 0);
        s[f][tt] = __builtin_amdgcn_mfma_f32_16x16x32_bf16(k1, qf[f][1], s[f][tt], 0, 0, 0);
      }
    }
    __builtin_amdgcn_s_setprio(0);

    // ---- p = exp2(s); pack; P_lds roundtrip; lsum via ones-MFMA ----
    s16x8 pf[2][2];
#pragma unroll
    for (int f = 0; f < 2; ++f) {
#pragma unroll
      for (int tt = 0; tt < 4; ++tt)
#pragma unroll
        for (int r = 0; r < 4; ++r)
          s[f][tt][r] = __builtin_amdgcn_exp2f(s[f][tt][r]);
#pragma unroll
      for (int tt = 0; tt < 4; ++tt) {
        u32x2 pw;
        pw.x = pack2bf_trunc(s[f][tt][0], s[f][tt][1]);
        pw.y = pack2bf_trunc(s[f][tt][2], s[f][tt][3]);
        const int off = (((tt * 2 + (lg >> 1)) ^ (lr & 7)) << 3) + ((lg & 1) << 2);
        *(u32x2*)&P_lds[w][lr][off] = pw;
      }
#pragma unroll
      for (int kvc = 0; kvc < 2; ++kvc)
        pf[f][kvc] = ldv<s16x8>(&P_lds[w][lr][((kvc * 4 + lg) ^ (lr & 7)) << 3]);
      lsum[f] = __builtin_amdgcn_mfma_f32_16x16x32_bf16(pf[f][0], onesv, lsum[f], 0, 0, 0);
      lsum[f] = __builtin_amdgcn_mfma_f32_16x16x32_bf16(pf[f][1], onesv, lsum[f], 0, 0, 0);
    }

    // ---- PV ----
    __builtin_amdgcn_s_setprio(1);
#pragma unroll
    for (int dt = 0; dt < 4; ++dt) {
      s16x8 v0 = ldv<s16x8>(&Vbuf[cur][(dt * 16 + lr) * 64 + ((lg ^ (lr & 7)) << 3)]);
      s16x8 v1 = ldv<s16x8>(&Vbuf[cur][(dt * 16 + lr) * 64 + (((4 + lg) ^ (lr & 7)) << 3)]);
#pragma unroll
      for (int f = 0; f < 2; ++f) {
        acc[f][dt] = __builtin_amdgcn_mfma_f32_16x16x32_bf16(pf[f][0], v0, acc[f][dt], 0, 0, 0);
        acc[f][dt] = __builtin_amdgcn_mfma_f32_16x16x32_bf16(pf[f][1], v1, acc[f][dt], 0, 0, 0);
      }
    }
    __builtin_amdgcn_s_setprio(0);
    __builtin_amdgcn_sched_barrier(0);
    __builtin_amdgcn_s_barrier();
  }
#undef STAGE

  const int b = bh >> 4, h = bh & 15;
#pragma unroll
  for (int f = 0; f < 2; ++f) {
    float li[4];
#pragma unroll
    for (int r = 0; r < 4; ++r) li[r] = __builtin_amdgcn_rcpf(lsum[f][r]);
#pragma unroll
    for (int dt = 0; dt < 4; ++dt)
#pragma unroll
      for (int r = 0; r < 4; ++r) {
        const int q = q0 + f * 16 + lg * 4 + r;
        Oattn[(size_t)((b << 11) + q) * 1024 + (h << 6) + dt * 16 + lr] =
            f2bf(acc[f][dt][r] * li[r]);
      }
  }
}

extern "C" void kernel_launch(void* const* d_in, const int* in_sizes, int n_in,
                              void* d_out, int out_size, void* d_ws, size_t ws_size,
                              hipStream_t stream) {
  const float* x  = (const float*)d_in[0];
  const float* Wq = (const float*)d_in[1];
  const float* bq = (const float*)d_in[2];
  const float* Wk = (const float*)d_in[3];
  const float* bk = (const float*)d_in[4];
  const float* Wv = (const float*)d_in[5];
  const float* bv = (const float*)d_in[6];
  const float* Wo = (const float*)d_in[7];
  const float* bo = (const float*)d_in[8];

  char* ws = (char*)d_ws;
  const size_t MB = 1u << 20;
  u16* xb = (u16*)(ws);              // 16 MB: x bf16 [8192][1024]
  u16* wt = (u16*)(ws + 16 * MB);    // 8 MB: 4x transposed bf16 weights [N][K]
  u16* Qh = (u16*)(ws + 24 * MB);    // 16 MB
  u16* Kh = (u16*)(ws + 40 * MB);    // 16 MB (swizzled)
  u16* Vt = (u16*)(ws + 56 * MB);    // 16 MB (transposed, swizzled)
  u16* attn = xb;                    // alias: x no longer needed after QKV GEMM

  const float qscale = 0.125f * 1.44269504088896f;  // fold 1/sqrt(64) and log2(e)

  cvt_x_k<<<dim3(8192), dim3(256), 0, stream>>>(x, xb);
  prep_w_k<<<dim3(16, 16, 4), dim3(256), 0, stream>>>(Wq, Wk, Wv, Wo, wt);
  gemm_qkv_k<<<dim3(32, 24), dim3(512), 0, stream>>>(xb, wt, bq, bk, bv, Qh, Kh, Vt, qscale);
  attn_k<<<dim3(16, 64), dim3(256), 0, stream>>>(Qh, Kh, Vt, attn);
  gemm_o_k<<<dim3(32, 8), dim3(512), 0, stream>>>(attn, wt + 3 * 1048576, bo, (float*)d_out);
}

// Round 13
// 201.695 us; speedup vs baseline: 1.1362x; 1.0456x over previous
//
#include <hip/hip_runtime.h>
#include <cstdint>

typedef unsigned short u16;
typedef uint32_t u32;
typedef float f32x4 __attribute__((ext_vector_type(4)));
typedef short s16x8 __attribute__((ext_vector_type(8)));
typedef u16 u16x4 __attribute__((ext_vector_type(4)));
typedef u32 u32x2 __attribute__((ext_vector_type(2)));
typedef u32 u32x4 __attribute__((ext_vector_type(4)));

__device__ __forceinline__ u16 f2bf(float f) {
  u32 u = __builtin_bit_cast(u32, f);
  u += 0x7FFFu + ((u >> 16) & 1u);
  return (u16)(u >> 16);
}

// pack two floats to (bf16(hi)<<16)|bf16(lo), truncating (bias cancels in p/sum ratio)
__device__ __forceinline__ u32 pack2bf_trunc(float lo, float hi) {
  return __builtin_amdgcn_perm(__builtin_bit_cast(u32, hi),
                               __builtin_bit_cast(u32, lo), 0x07060302u);
}

template <typename T>
__device__ __forceinline__ T ldv(const void* p) {
  T v;
  __builtin_memcpy(&v, __builtin_assume_aligned(p, 16), sizeof(T));
  return v;
}

__device__ __forceinline__ void gload_lds16(const void* g, void* l) {
  __builtin_amdgcn_global_load_lds((const __attribute__((address_space(1))) void*)g,
                                   (__attribute__((address_space(3))) void*)l, 16, 0, 0);
}

// ---------------- convert x (fp32 -> bf16) ----------------
__global__ __launch_bounds__(256) void cvt_x_k(const float* __restrict__ in,
                                               u16* __restrict__ out) {
  const int i = (blockIdx.x * 256 + threadIdx.x) * 4;
  float4 v = *(const float4*)(in + i);
  u16x4 o;
  o.x = f2bf(v.x); o.y = f2bf(v.y); o.z = f2bf(v.z); o.w = f2bf(v.w);
  *(u16x4*)(out + i) = o;
}

// ---------------- transpose weights (fp32 [K][N] -> bf16 [N][K]) ----------------
__global__ __launch_bounds__(256) void prep_w_k(const float* __restrict__ Wq,
                                                const float* __restrict__ Wk,
                                                const float* __restrict__ Wv,
                                                const float* __restrict__ Wo,
                                                u16* __restrict__ out) {
  __shared__ u16 t[64][72];
  const float* W = (blockIdx.z == 0) ? Wq : (blockIdx.z == 1) ? Wk
                  : (blockIdx.z == 2) ? Wv : Wo;
  u16* O = out + (size_t)blockIdx.z * 1024 * 1024;
  const int n0 = blockIdx.x * 64, k0 = blockIdx.y * 64;
  const int tid = threadIdx.x;
#pragma unroll
  for (int i = 0; i < 16; ++i) {
    int e = i * 256 + tid;
    int r = e >> 6, c = e & 63;
    t[r][c] = f2bf(W[(size_t)(k0 + r) * 1024 + n0 + c]);
  }
  __syncthreads();
#pragma unroll
  for (int i = 0; i < 16; ++i) {
    int e = i * 256 + tid;
    int rr = e >> 6, cc = e & 63;
    O[(size_t)(n0 + rr) * 1024 + k0 + cc] = t[cc][rr];
  }
}

// ---------------- fused QKV GEMM: 256x128 tile, 8 waves, triple-buffered, DE-PINNED ----
// r13: all sched_barrier(0) removed (m141: order-pinning -> 510 TF, our exact region).
// vmcnt asm ("memory") + raw s_barrier only; compiler free to hoist addr-calc /
// overlap ds_read with MFMA within phases.
__global__ __launch_bounds__(512, 2) void gemm_qkv_k(const u16* __restrict__ A,
                                                     const u16* __restrict__ Wt,
                                                     const float* __restrict__ bq,
                                                     const float* __restrict__ bk,
                                                     const float* __restrict__ bv,
                                                     u16* __restrict__ Qh,
                                                     u16* __restrict__ Kh,
                                                     u16* __restrict__ Vt,
                                                     float qscale) {
  constexpr int K = 1024;
  __shared__ __attribute__((aligned(16))) u16 As[3][256][64];
  __shared__ __attribute__((aligned(16))) u16 Bs[3][128][64];
  const int tid = threadIdx.x;
  const int l = tid & 63, w = tid >> 6;
  const int lr = l & 15, lg = l >> 4;
  const int m0 = blockIdx.x * 256;
  const int ng = blockIdx.y * 128;
  const int seg = ng >> 10;
  const int n0 = ng & 1023;
  const u16* Bt = Wt + ((size_t)seg << 20);
  const int wr = (w >> 1) * 64, wc = (w & 1) * 64;
  const int rT = tid >> 3;
  const int cSw = (((tid & 7) ^ (rT & 7)) << 3);

  f32x4 acc[4][4] = {};

#define GSTAGE(buf, kt)                                                         \
  do {                                                                          \
    _Pragma("unroll")                                                           \
    for (int i = 0; i < 4; ++i)                                                 \
      gload_lds16(A + (size_t)(m0 + i * 64 + rT) * K + (kt) + cSw,              \
                  &As[buf][i * 64][0] + (size_t)w * 512);                       \
    _Pragma("unroll")                                                           \
    for (int i = 0; i < 2; ++i)                                                 \
      gload_lds16(Bt + (size_t)(n0 + i * 64 + rT) * K + (kt) + cSw,             \
                  &Bs[buf][i * 64][0] + (size_t)w * 512);                       \
  } while (0)

  GSTAGE(0, 0);
  GSTAGE(1, 64);
  asm volatile("s_waitcnt vmcnt(6)" ::: "memory");
  __builtin_amdgcn_s_barrier();

  int bcur = 0, bst = 2;
  for (int t = 0; t < 16; ++t) {
    if (t < 14) {
      GSTAGE(bst, (t + 2) * 64);
      asm volatile("s_waitcnt vmcnt(12)" ::: "memory");
    } else if (t == 14) {
      asm volatile("s_waitcnt vmcnt(6)" ::: "memory");
    } else {
      asm volatile("s_waitcnt vmcnt(0)" ::: "memory");
    }
    __builtin_amdgcn_s_barrier();
#pragma unroll
    for (int kk = 0; kk < 2; ++kk) {
      s16x8 a[4], b[4];
#pragma unroll
      for (int mi = 0; mi < 4; ++mi)
        a[mi] = ldv<s16x8>(&As[bcur][wr + mi * 16 + lr][((kk * 4 + lg) ^ (lr & 7)) << 3]);
#pragma unroll
      for (int ni = 0; ni < 4; ++ni)
        b[ni] = ldv<s16x8>(&Bs[bcur][wc + ni * 16 + lr][((kk * 4 + lg) ^ (lr & 7)) << 3]);
#pragma unroll
      for (int mi = 0; mi < 4; ++mi)
#pragma unroll
        for (int ni = 0; ni < 4; ++ni)
          acc[mi][ni] = __builtin_amdgcn_mfma_f32_16x16x32_bf16(a[mi], b[ni], acc[mi][ni], 0, 0, 0);
    }
    __builtin_amdgcn_s_barrier();  // buf t reads retired before its overwrite (issued t+1)
    bcur = (bcur == 2) ? 0 : bcur + 1;
    bst = (bst == 2) ? 0 : bst + 1;
  }
#undef GSTAGE

  const float* bias = (seg == 0) ? bq : (seg == 1) ? bk : bv;
  const float scale = (seg == 0) ? qscale : 1.0f;
  u16* outp = (seg == 0) ? Qh : (seg == 1) ? Kh : Vt;

  // ---- coalesced epilogue via swizzled LDS staging (reuse As[0]: [256][64]) ----
  u16* Cb = &As[0][0][0];
  const int bb = m0 >> 11;
  const int sbase = m0 & 2047;

#pragma unroll
  for (int p = 0; p < 2; ++p) {
    __syncthreads();
    if ((wc >> 6) == p) {
#pragma unroll
      for (int ni = 0; ni < 4; ++ni) {
        const int c = ni * 16 + lr;
        const float bvv = bias[n0 + p * 64 + c];
#pragma unroll
        for (int mi = 0; mi < 4; ++mi) {
#pragma unroll
          for (int r = 0; r < 4; ++r) {
            const int row = wr + mi * 16 + lg * 4 + r;
            Cb[row * 64 + ((((c >> 3) ^ (row & 7)) << 3) | (c & 7))] =
                f2bf((acc[mi][ni][r] + bvv) * scale);
          }
        }
      }
    }
    __syncthreads();
    const int h = (n0 + p * 64) >> 6;
    if (seg <= 1) {
      const int row = tid >> 1;
      const int s = sbase + row;
#pragma unroll
      for (int j = 0; j < 4; ++j) {
        const int c = (tid & 1) * 32 + j * 8;
        s16x8 v = ldv<s16x8>(&Cb[row * 64 + (((c >> 3) ^ (row & 7)) << 3)]);
        const int chunk = (seg == 0) ? (c >> 3) : (((c >> 3) ^ (s & 7)) & 7);
        *(s16x8*)(outp + ((size_t)((bb << 4) + h) * 2048 + s) * 64 + (chunk << 3)) = v;
      }
    } else {
      const int hd = tid & 63;
#pragma unroll
      for (int j = 0; j < 4; ++j) {
        const int s0 = (tid >> 6) * 32 + j * 8;
        u16 vals[8];
#pragma unroll
        for (int i = 0; i < 8; ++i) {
          const int row = s0 + i;
          vals[i] = Cb[row * 64 + ((((hd >> 3) ^ (row & 7)) << 3) | (hd & 7))];
        }
        const int sl = sbase + s0;
        const int swz = (((sl >> 3) & 7) ^ (hd & 7)) & 7;
        *(s16x8*)(outp + ((size_t)((bb << 4) + h) * 64 + hd) * 2048 +
                  ((sl & ~63) | (swz << 3))) = *(s16x8*)vals;
      }
    }
  }
}

// ---------------- final GEMM: 256x128 tile, triple-buffered, de-pinned, fp32 out ------
__global__ __launch_bounds__(512, 2) void gemm_o_k(const u16* __restrict__ A,
                                                   const u16* __restrict__ Bt,
                                                   const float* __restrict__ bias,
                                                   float* __restrict__ outp) {
  constexpr int K = 1024;
  __shared__ __attribute__((aligned(16))) u16 As[3][256][64];
  __shared__ __attribute__((aligned(16))) u16 Bs[3][128][64];
  const int tid = threadIdx.x;
  const int l = tid & 63, w = tid >> 6;
  const int lr = l & 15, lg = l >> 4;
  const int m0 = blockIdx.x * 256, n0 = blockIdx.y * 128;
  const int wr = (w >> 1) * 64, wc = (w & 1) * 64;
  const int rT = tid >> 3;
  const int cSw = (((tid & 7) ^ (rT & 7)) << 3);

  f32x4 acc[4][4] = {};

#define GSTAGE(buf, kt)                                                         \
  do {                                                                          \
    _Pragma("unroll")                                                           \
    for (int i = 0; i < 4; ++i)                                                 \
      gload_lds16(A + (size_t)(m0 + i * 64 + rT) * K + (kt) + cSw,              \
                  &As[buf][i * 64][0] + (size_t)w * 512);                       \
    _Pragma("unroll")                                                           \
    for (int i = 0; i < 2; ++i)                                                 \
      gload_lds16(Bt + (size_t)(n0 + i * 64 + rT) * K + (kt) + cSw,             \
                  &Bs[buf][i * 64][0] + (size_t)w * 512);                       \
  } while (0)

  GSTAGE(0, 0);
  GSTAGE(1, 64);
  asm volatile("s_waitcnt vmcnt(6)" ::: "memory");
  __builtin_amdgcn_s_barrier();

  int bcur = 0, bst = 2;
  for (int t = 0; t < 16; ++t) {
    if (t < 14) {
      GSTAGE(bst, (t + 2) * 64);
      asm volatile("s_waitcnt vmcnt(12)" ::: "memory");
    } else if (t == 14) {
      asm volatile("s_waitcnt vmcnt(6)" ::: "memory");
    } else {
      asm volatile("s_waitcnt vmcnt(0)" ::: "memory");
    }
    __builtin_amdgcn_s_barrier();
#pragma unroll
    for (int kk = 0; kk < 2; ++kk) {
      s16x8 a[4], b[4];
#pragma unroll
      for (int mi = 0; mi < 4; ++mi)
        a[mi] = ldv<s16x8>(&As[bcur][wr + mi * 16 + lr][((kk * 4 + lg) ^ (lr & 7)) << 3]);
#pragma unroll
      for (int ni = 0; ni < 4; ++ni)
        b[ni] = ldv<s16x8>(&Bs[bcur][wc + ni * 16 + lr][((kk * 4 + lg) ^ (lr & 7)) << 3]);
#pragma unroll
      for (int mi = 0; mi < 4; ++mi)
#pragma unroll
        for (int ni = 0; ni < 4; ++ni)
          acc[mi][ni] = __builtin_amdgcn_mfma_f32_16x16x32_bf16(a[mi], b[ni], acc[mi][ni], 0, 0, 0);
    }
    __builtin_amdgcn_s_barrier();
    bcur = (bcur == 2) ? 0 : bcur + 1;
    bst = (bst == 2) ? 0 : bst + 1;
  }
#undef GSTAGE

#pragma unroll
  for (int ni = 0; ni < 4; ++ni) {
    const int col = n0 + wc + ni * 16 + lr;
    const float bv = bias[col];
#pragma unroll
    for (int mi = 0; mi < 4; ++mi)
#pragma unroll
      for (int r = 0; r < 4; ++r) {
        const int rowm = m0 + wr + mi * 16 + lg * 4 + r;
        outp[(size_t)rowm * 1024 + col] = acc[mi][ni][r] + bv;
      }
  }
}

// ---------------- flash attention v7: f=4 (wave owns 64 q-rows) ----------------
// LDS-traffic theory: K/V ds_reads per FLOP halve vs f=2. 4 waves/block,
// grid (8,64) = 512 blocks = exactly 2/CU. QK processed per kv-half (s2[4][2])
// to cap liveness. No-max softmax; lsum via ones-MFMA; de-pinned.
__global__ __launch_bounds__(256, 2) void attn_k(const u16* __restrict__ Qh,
                                                 const u16* __restrict__ Kg,
                                                 const u16* __restrict__ Vg,
                                                 u16* __restrict__ Oattn) {
  __shared__ __attribute__((aligned(16))) u16 Kbuf[2][4096];
  __shared__ __attribute__((aligned(16))) u16 Vbuf[2][4096];
  __shared__ __attribute__((aligned(16))) u16 P_lds[4][16][64];
  const int tid = threadIdx.x, l = tid & 63, w = tid >> 6;
  const int lr = l & 15, lg = l >> 4;
  const int bh = blockIdx.y;
  const int q0 = blockIdx.x * 256 + w * 64;
  const u16* Q = Qh + (size_t)bh * (2048 * 64);
  const u16* K = Kg + (size_t)bh * (2048 * 64);
  const u16* V = Vg + (size_t)bh * (64 * 2048);

  s16x8 qf[4][2];
#pragma unroll
  for (int f = 0; f < 4; ++f)
#pragma unroll
    for (int kk = 0; kk < 2; ++kk)
      qf[f][kk] = ldv<s16x8>(Q + (size_t)(q0 + f * 16 + lr) * 64 + kk * 32 + lg * 8);

  const u32 one2 = 0x3F803F80u;  // two bf16 1.0
  const s16x8 onesv = __builtin_bit_cast(s16x8, (u32x4){one2, one2, one2, one2});

  f32x4 acc[4][4] = {};
  f32x4 lsum[4] = {};

#define STAGE(buf, kv0)                                                                 \
  do {                                                                                  \
    gload_lds16(K + (size_t)(kv0) * 64 + (size_t)tid * 8, &Kbuf[buf][w * 512]);         \
    gload_lds16(K + (size_t)(kv0) * 64 + 2048 + (size_t)tid * 8,                        \
                &Kbuf[buf][2048 + w * 512]);                                            \
    gload_lds16(V + (size_t)(tid >> 3) * 2048 + (kv0) + (tid & 7) * 8,                  \
                &Vbuf[buf][w * 512]);                                                   \
    gload_lds16(V + (size_t)((tid >> 3) + 32) * 2048 + (kv0) + (tid & 7) * 8,           \
                &Vbuf[buf][2048 + w * 512]);                                            \
  } while (0)

  STAGE(0, 0);

  for (int t = 0; t < 32; ++t) {
    const int cur = t & 1;
    if (t < 31) {
      STAGE(cur ^ 1, (t + 1) * 64);
      asm volatile("s_waitcnt vmcnt(4)" ::: "memory");  // cur's 4 retired
    } else {
      asm volatile("s_waitcnt vmcnt(0)" ::: "memory");
    }
    __builtin_amdgcn_s_barrier();

    s16x8 pf[4][2];
#pragma unroll
    for (int kvc = 0; kvc < 2; ++kvc) {
      // ---- QK^T for this kv-half: s2[f][t2], liveness capped at 32 VGPR ----
      f32x4 s2[4][2] = {};
      __builtin_amdgcn_s_setprio(1);
#pragma unroll
      for (int t2 = 0; t2 < 2; ++t2) {
        const int tt = kvc * 2 + t2;
        s16x8 k0 = ldv<s16x8>(&Kbuf[cur][(tt * 16 + lr) * 64 + ((lg ^ (lr & 7)) << 3)]);
        s16x8 k1 = ldv<s16x8>(&Kbuf[cur][(tt * 16 + lr) * 64 + (((4 + lg) ^ (lr & 7)) << 3)]);
#pragma unroll
        for (int f = 0; f < 4; ++f) {
          s2[f][t2] = __builtin_amdgcn_mfma_f32_16x16x32_bf16(k0, qf[f][0], s2[f][t2], 0, 0, 0);
          s2[f][t2] = __builtin_amdgcn_mfma_f32_16x16x32_bf16(k1, qf[f][1], s2[f][t2], 0, 0, 0);
        }
      }
      __builtin_amdgcn_s_setprio(0);

      // ---- p = exp2(s); pack; P_lds roundtrip (per f, wave-private); lsum ----
#pragma unroll
      for (int f = 0; f < 4; ++f) {
#pragma unroll
        for (int t2 = 0; t2 < 2; ++t2)
#pragma unroll
          for (int r = 0; r < 4; ++r)
            s2[f][t2][r] = __builtin_amdgcn_exp2f(s2[f][t2][r]);
#pragma unroll
        for (int t2 = 0; t2 < 2; ++t2) {
          const int tt = kvc * 2 + t2;
          u32x2 pw;
          pw.x = pack2bf_trunc(s2[f][t2][0], s2[f][t2][1]);
          pw.y = pack2bf_trunc(s2[f][t2][2], s2[f][t2][3]);
          const int off = (((tt * 2 + (lg >> 1)) ^ (lr & 7)) << 3) + ((lg & 1) << 2);
          *(u32x2*)&P_lds[w][lr][off] = pw;
        }
        pf[f][kvc] = ldv<s16x8>(&P_lds[w][lr][((kvc * 4 + lg) ^ (lr & 7)) << 3]);
        lsum[f] = __builtin_amdgcn_mfma_f32_16x16x32_bf16(pf[f][kvc], onesv, lsum[f], 0, 0, 0);
      }
    }

    // ---- PV ----
    __builtin_amdgcn_s_setprio(1);
#pragma unroll
    for (int dt = 0; dt < 4; ++dt) {
      s16x8 v0 = ldv<s16x8>(&Vbuf[cur][(dt * 16 + lr) * 64 + ((lg ^ (lr & 7)) << 3)]);
      s16x8 v1 = ldv<s16x8>(&Vbuf[cur][(dt * 16 + lr) * 64 + (((4 + lg) ^ (lr & 7)) << 3)]);
#pragma unroll
      for (int f = 0; f < 4; ++f) {
        acc[f][dt] = __builtin_amdgcn_mfma_f32_16x16x32_bf16(pf[f][0], v0, acc[f][dt], 0, 0, 0);
        acc[f][dt] = __builtin_amdgcn_mfma_f32_16x16x32_bf16(pf[f][1], v1, acc[f][dt], 0, 0, 0);
      }
    }
    __builtin_amdgcn_s_setprio(0);
    __builtin_amdgcn_s_barrier();  // Kbuf/Vbuf[cur] reads done before next-iter overwrite
  }
#undef STAGE

  const int b = bh >> 4, h = bh & 15;
#pragma unroll
  for (int f = 0; f < 4; ++f) {
    float li[4];
#pragma unroll
    for (int r = 0; r < 4; ++r) li[r] = __builtin_amdgcn_rcpf(lsum[f][r]);
#pragma unroll
    for (int dt = 0; dt < 4; ++dt)
#pragma unroll
      for (int r = 0; r < 4; ++r) {
        const int q = q0 + f * 16 + lg * 4 + r;
        Oattn[(size_t)((b << 11) + q) * 1024 + (h << 6) + dt * 16 + lr] =
            f2bf(acc[f][dt][r] * li[r]);
      }
  }
}

extern "C" void kernel_launch(void* const* d_in, const int* in_sizes, int n_in,
                              void* d_out, int out_size, void* d_ws, size_t ws_size,
                              hipStream_t stream) {
  const float* x  = (const float*)d_in[0];
  const float* Wq = (const float*)d_in[1];
  const float* bq = (const float*)d_in[2];
  const float* Wk = (const float*)d_in[3];
  const float* bk = (const float*)d_in[4];
  const float* Wv = (const float*)d_in[5];
  const float* bv = (const float*)d_in[6];
  const float* Wo = (const float*)d_in[7];
  const float* bo = (const float*)d_in[8];

  char* ws = (char*)d_ws;
  const size_t MB = 1u << 20;
  u16* xb = (u16*)(ws);              // 16 MB: x bf16 [8192][1024]
  u16* wt = (u16*)(ws + 16 * MB);    // 8 MB: 4x transposed bf16 weights [N][K]
  u16* Qh = (u16*)(ws + 24 * MB);    // 16 MB
  u16* Kh = (u16*)(ws + 40 * MB);    // 16 MB (swizzled)
  u16* Vt = (u16*)(ws + 56 * MB);    // 16 MB (transposed, swizzled)
  u16* attn = xb;                    // alias: x no longer needed after QKV GEMM

  const float qscale = 0.125f * 1.44269504088896f;  // fold 1/sqrt(64) and log2(e)

  cvt_x_k<<<dim3(8192), dim3(256), 0, stream>>>(x, xb);
  prep_w_k<<<dim3(16, 16, 4), dim3(256), 0, stream>>>(Wq, Wk, Wv, Wo, wt);
  gemm_qkv_k<<<dim3(32, 24), dim3(512), 0, stream>>>(xb, wt, bq, bk, bv, Qh, Kh, Vt, qscale);
  attn_k<<<dim3(8, 64), dim3(256), 0, stream>>>(Qh, Kh, Vt, attn);
  gemm_o_k<<<dim3(32, 8), dim3(512), 0, stream>>>(attn, wt + 3 * 1048576, bo, (float*)d_out);
}